// Round 1
// baseline (843.292 us; speedup 1.0000x reference)
//
#include <hip/hip_runtime.h>
#include <math.h>

#define BB 2
#define CC 192
#define DD 32
#define HH 48
#define WW 48
#define HWs (HH*WW)            // 2304
#define SS (DD*HH*WW)          // 73728
#define BS (BB*SS)             // 147456
#define NTOT (BB*CC*SS)        // 28311552
#define EPSV 1e-6f

// ---------------- K1: channel LayerNorm stats + a = silu(qk) ----------------
__global__ __launch_bounds__(256) void k1_ln_a(
    const float* __restrict__ xs, const float* __restrict__ xt,
    const float* __restrict__ ln_w, const float* __restrict__ ln_b,
    const float* __restrict__ qk_sp_w, const float* __restrict__ qk_sp_b,
    const float* __restrict__ qk_tm_w, const float* __restrict__ qk_tm_b,
    float* __restrict__ a_out, float* __restrict__ stats)
{
    __shared__ float w_lnw[CC], w_lnb[CC], w_qsw[CC], w_qsb[CC], w_qtw[CC], w_qtb[CC];
    int tid = threadIdx.x;
    if (tid < CC) {
        w_lnw[tid] = ln_w[tid];  w_lnb[tid] = ln_b[tid];
        w_qsw[tid] = qk_sp_w[tid]; w_qsb[tid] = qk_sp_b[tid];
        w_qtw[tid] = qk_tm_w[tid]; w_qtb[tid] = qk_tm_b[tid];
    }
    __syncthreads();
    int p = blockIdx.x * 256 + tid;          // [0, BS)
    int b = p / SS, s = p % SS;
    const float* xsp = xs + (size_t)b * CC * SS + s;
    const float* xtp = xt + (size_t)b * CC * SS + s;

    float sum = 0.f, ssum = 0.f;
    #pragma unroll 4
    for (int c = 0; c < CC; ++c) {
        float v = xsp[(size_t)c * SS];
        sum += v; ssum += v * v;
    }
    float mean = sum * (1.0f / CC);
    float var  = ssum * (1.0f / CC) - mean * mean;
    float rstd = rsqrtf(var + EPSV);
    stats[p] = mean;
    stats[BS + p] = rstd;

    float* ap = a_out + (size_t)b * CC * SS + s;
    #pragma unroll 2
    for (int c = 0; c < CC; ++c) {
        float v = xsp[(size_t)c * SS];
        float t = xtp[(size_t)c * SS];
        float xn = (v - mean) * rstd * w_lnw[c] + w_lnb[c];
        float qk = xn * w_qsw[c] + w_qsb[c] + t * w_qtw[c] + w_qtb[c];
        float av = qk / (1.f + __expf(-qk));   // silu
        ap[(size_t)c * SS] = av;
    }
}

// ---------------- K2: depthwise dilated conv + v-recompute + x + ssq --------
#define DT 8
#define HT 12
#define TD (DT+6)    // 14
#define TH (HT+6)    // 18
#define TWD 56
#define TILE_N (TD*TH*TWD)   // 14112

__global__ __launch_bounds__(192) void k2_conv(
    const float* __restrict__ a_in, const float* __restrict__ xs,
    const float* __restrict__ xt, const float* __restrict__ stats,
    const float* __restrict__ attn_w, const float* __restrict__ attn_b,
    const float* __restrict__ ln_w, const float* __restrict__ ln_b,
    const float* __restrict__ v_sp_w, const float* __restrict__ v_sp_b,
    const float* __restrict__ v_tm_w, const float* __restrict__ v_tm_b,
    float* __restrict__ x_out, float* __restrict__ ssq)
{
    __shared__ float tile[TILE_N];
    __shared__ float wts[64];
    __shared__ float red[4];
    int tid = threadIdx.x;
    int blk = blockIdx.x;                 // bc*16 + dchunk*4 + hchunk
    int bc = blk >> 4;
    int d0 = ((blk >> 2) & 3) * DT;
    int h0 = (blk & 3) * HT;
    int b = bc / CC, c = bc % CC;

    const float* abase = a_in + (size_t)bc * SS;
    for (int i = tid; i < TILE_N; i += 192) {
        int dz = i / (TH*TWD); int r = i % (TH*TWD);
        int hz = r / TWD, wz = r % TWD;
        int gd = d0 - 3 + dz, gh = h0 - 3 + hz, gw = wz - 3;
        float v = 0.f;
        if ((unsigned)gd < DD && (unsigned)gh < HH && (unsigned)gw < WW)
            v = abase[gd * HWs + gh * WW + gw];
        tile[i] = v;
    }
    if (tid < 64) wts[tid] = attn_w[c * 64 + tid];
    float bias = attn_b[c];
    float lnw = ln_w[c], lnb = ln_b[c];
    float vsw = v_sp_w[c], vsb = v_sp_b[c];
    float vtw = v_tm_w[c], vtb = v_tm_b[c];
    __syncthreads();

    float ssql = 0.f;
    for (int task = tid; task < DT*HT*6; task += 192) {
        int od = task / (HT*6); int r = task % (HT*6);
        int oh = r / 6, ow0 = (r % 6) * 8;

        float acc[8];
        #pragma unroll
        for (int j = 0; j < 8; ++j) acc[j] = 0.f;

        #pragma unroll
        for (int kd = 0; kd < 4; ++kd) {
            int dz = od + 2 * kd;
            #pragma unroll
            for (int kh = 0; kh < 4; ++kh) {
                int hz = oh + 2 * kh;
                const float* rp = &tile[(dz * TH + hz) * TWD + ow0];
                float win[16];
                ((float4*)win)[0] = *(const float4*)(rp);
                ((float4*)win)[1] = *(const float4*)(rp + 4);
                ((float4*)win)[2] = *(const float4*)(rp + 8);
                ((float4*)win)[3] = *(const float4*)(rp + 12);
                float wvf[4];
                *(float4*)wvf = *(const float4*)&wts[(kd * 4 + kh) * 4];
                #pragma unroll
                for (int kw = 0; kw < 4; ++kw) {
                    float wk = wvf[kw];
                    #pragma unroll
                    for (int j = 0; j < 8; ++j)
                        acc[j] = fmaf(win[j + 2 * kw], wk, acc[j]);
                }
            }
        }

        int spat = (d0 + od) * HWs + (h0 + oh) * WW + ow0;
        size_t g = (size_t)bc * SS + spat;
        int sp = b * SS + spat;
        float xsv[8], xtv[8], mnv[8], rsv[8], xov[8];
        ((float4*)xsv)[0] = *(const float4*)&xs[g];
        ((float4*)xsv)[1] = *(const float4*)&xs[g + 4];
        ((float4*)xtv)[0] = *(const float4*)&xt[g];
        ((float4*)xtv)[1] = *(const float4*)&xt[g + 4];
        ((float4*)mnv)[0] = *(const float4*)&stats[sp];
        ((float4*)mnv)[1] = *(const float4*)&stats[sp + 4];
        ((float4*)rsv)[0] = *(const float4*)&stats[BS + sp];
        ((float4*)rsv)[1] = *(const float4*)&stats[BS + sp + 4];
        #pragma unroll
        for (int j = 0; j < 8; ++j) {
            float xn = (xsv[j] - mnv[j]) * rsv[j] * lnw + lnb;
            float vv = xn * vsw + vsb + xtv[j] * vtw + vtb;
            float xo = (acc[j] + bias) * vv;
            xov[j] = xo;
            ssql += xo * xo;
        }
        *(float4*)&x_out[g]     = ((float4*)xov)[0];
        *(float4*)&x_out[g + 4] = ((float4*)xov)[1];
    }

    // block reduce ssql (192 threads = 3 waves)
    int lane = tid & 63, wid = tid >> 6;
    #pragma unroll
    for (int off = 32; off > 0; off >>= 1)
        ssql += __shfl_down(ssql, off);
    if (lane == 0) red[wid] = ssql;
    __syncthreads();
    if (tid == 0) atomicAdd(&ssq[bc], red[0] + red[1] + red[2]);
}

// ---------------- K3: GRN scalars -> per-(b,c) A, B2 ----------------------
__global__ __launch_bounds__(384) void k3_scale(
    const float* __restrict__ ssq,
    const float* __restrict__ grn_gamma, const float* __restrict__ grn_beta,
    const float* __restrict__ proj_w, const float* __restrict__ proj_b,
    float* __restrict__ AB)
{
    __shared__ float gxs[BB*CC];
    __shared__ float msum[BB];
    int tid = threadIdx.x;     // 384
    float gx = sqrtf(ssq[tid]);
    gxs[tid] = gx;
    __syncthreads();
    if (tid < BB) {
        float s = 0.f;
        for (int c2 = 0; c2 < CC; ++c2) s += gxs[tid * CC + c2];
        msum[tid] = s * (1.0f / CC);
    }
    __syncthreads();
    int b = tid / CC, c2 = tid % CC;
    float nx = gx / (msum[b] + EPSV);
    float A  = proj_w[c2] * (1.f + grn_gamma[c2] * nx);
    float B2 = proj_w[c2] * grn_beta[c2] + proj_b[c2];
    AB[tid] = A;
    AB[BB*CC + tid] = B2;
}

// ---------------- K4: out = xs + A*x + B2 ---------------------------------
__global__ __launch_bounds__(256) void k4_final(
    const float* __restrict__ xs, const float* __restrict__ xv,
    const float* __restrict__ AB, float* __restrict__ out)
{
    int i = blockIdx.x * 256 + threadIdx.x;    // float4 index
    size_t g = (size_t)i * 4;
    int bc = (int)(g / SS);
    float A  = AB[bc];
    float B2 = AB[BB*CC + bc];
    float4 x4 = *(const float4*)&xv[g];
    float4 s4 = *(const float4*)&xs[g];
    float4 o;
    o.x = fmaf(A, x4.x, s4.x) + B2;
    o.y = fmaf(A, x4.y, s4.y) + B2;
    o.z = fmaf(A, x4.z, s4.z) + B2;
    o.w = fmaf(A, x4.w, s4.w) + B2;
    *(float4*)&out[g] = o;
}

extern "C" void kernel_launch(void* const* d_in, const int* in_sizes, int n_in,
                              void* d_out, int out_size, void* d_ws, size_t ws_size,
                              hipStream_t stream) {
    const float* xs      = (const float*)d_in[0];
    const float* xt      = (const float*)d_in[1];
    const float* ln_w    = (const float*)d_in[2];
    const float* ln_b    = (const float*)d_in[3];
    const float* qk_sp_w = (const float*)d_in[4];
    const float* qk_sp_b = (const float*)d_in[5];
    const float* v_sp_w  = (const float*)d_in[6];
    const float* v_sp_b  = (const float*)d_in[7];
    const float* qk_tm_w = (const float*)d_in[8];
    const float* qk_tm_b = (const float*)d_in[9];
    const float* v_tm_w  = (const float*)d_in[10];
    const float* v_tm_b  = (const float*)d_in[11];
    const float* attn_w  = (const float*)d_in[12];
    const float* attn_b  = (const float*)d_in[13];
    const float* grn_g   = (const float*)d_in[14];
    const float* grn_b   = (const float*)d_in[15];
    const float* proj_w  = (const float*)d_in[16];
    const float* proj_b  = (const float*)d_in[17];
    float* out = (float*)d_out;

    float* ws    = (float*)d_ws;
    float* a_buf = ws;                    // NTOT
    float* x_buf = ws + (size_t)NTOT;     // NTOT
    float* stats = ws + (size_t)2*NTOT;   // 2*BS
    float* ssq   = stats + (size_t)2*BS;  // BB*CC
    float* AB    = ssq + BB*CC;           // 2*BB*CC

    hipMemsetAsync(ssq, 0, BB*CC*sizeof(float), stream);

    k1_ln_a<<<BS/256, 256, 0, stream>>>(xs, xt, ln_w, ln_b,
        qk_sp_w, qk_sp_b, qk_tm_w, qk_tm_b, a_buf, stats);

    k2_conv<<<BB*CC*16, 192, 0, stream>>>(a_buf, xs, xt, stats,
        attn_w, attn_b, ln_w, ln_b, v_sp_w, v_sp_b, v_tm_w, v_tm_b,
        x_buf, ssq);

    k3_scale<<<1, 384, 0, stream>>>(ssq, grn_g, grn_b, proj_w, proj_b, AB);

    k4_final<<<NTOT/4/256, 256, 0, stream>>>(xs, x_buf, AB, out);
}